// Round 16
// baseline (40.880 us; speedup 1.0000x reference)
//
#include <hip/hip_runtime.h>

#define DIMS 1024
#define DEXT 512         // bytes/row: 512 fp4 data (norms handled in epilogue)
#define KNN_K 8
#define BM 128
#define BN 128

typedef float f32x4 __attribute__((ext_vector_type(4)));
typedef int i32x4 __attribute__((ext_vector_type(4)));
typedef int i32x8 __attribute__((ext_vector_type(8)));

#define CVT(a, b, old, w) __builtin_amdgcn_cvt_pk_fp8_f32((a), (b), (old), (w))
#define SCL1 0x7f7f7f7f  // E8M0 127 -> x1
#define SCL2 0x80808080  // E8M0 128 -> x2 (folds the -2 into -y's scale)

// compare-exchange (ascending)
__device__ __forceinline__ void ce(float& a, float& b) {
  float lo = fminf(a, b), hi = fmaxf(a, b); a = lo; b = hi;
}
// Batcher odd-even merge sort, 8 elements ascending (19 CE, branch-free)
__device__ __forceinline__ void sort8(float (&v)[8]) {
  ce(v[0],v[1]); ce(v[2],v[3]); ce(v[4],v[5]); ce(v[6],v[7]);
  ce(v[0],v[2]); ce(v[1],v[3]); ce(v[4],v[6]); ce(v[5],v[7]);
  ce(v[1],v[2]); ce(v[5],v[6]);
  ce(v[0],v[4]); ce(v[1],v[5]); ce(v[2],v[6]); ce(v[3],v[7]);
  ce(v[2],v[4]); ce(v[3],v[5]);
  ce(v[1],v[2]); ce(v[3],v[4]); ce(v[5],v[6]);
}
// a,b ascending sorted-8 -> a = smallest 8 of union, ascending
__device__ __forceinline__ void merge8(float (&a)[8], const float (&b)[8]) {
  float u[8];
  #pragma unroll
  for (int k = 0; k < 8; ++k) u[k] = fminf(a[k], b[7 - k]);  // bitonic
  ce(u[0],u[4]); ce(u[1],u[5]); ce(u[2],u[6]); ce(u[3],u[7]);
  ce(u[0],u[2]); ce(u[1],u[3]); ce(u[4],u[6]); ce(u[5],u[7]);
  ce(u[0],u[1]); ce(u[2],u[3]); ce(u[4],u[5]); ce(u[6],u[7]);
  #pragma unroll
  for (int k = 0; k < 8; ++k) a[k] = u[k];
}

__device__ __forceinline__ void gload_lds16(const void* g, void* l) {
  __builtin_amdgcn_global_load_lds(
      (const __attribute__((address_space(1))) void*)g,
      (__attribute__((address_space(3))) void*)l, 16, 0, 0);
}

// e2m1 quantize (round-to-nearest): {0,.5,1,1.5,2,3,4,6} + sign
__device__ __forceinline__ unsigned q4(float v) {
  float a = fabsf(v);
  unsigned code = (a >= 0.25f) + (a >= 0.75f) + (a >= 1.25f) + (a >= 1.75f)
                + (a >= 2.5f) + (a >= 3.5f) + (a >= 5.f);
  return (v < 0.f ? 8u : 0u) | code;
}

// ---- prep: norms + fp4 pack (x, -y) + min_dists->out copy ------------------
// Data MFMA uses scale 2 on the (-y) operand => acc = -2 x.y; epilogue adds
// exact f32 x2[r] + y2[c] => squared distance.
template<bool PRE>
__global__ void prep_kernel(const float* __restrict__ x, const float* __restrict__ y,
                            float* __restrict__ x2, float* __restrict__ y2,
                            char* __restrict__ xb, char* __restrict__ yb,
                            const float4* __restrict__ mind4, float4* __restrict__ out4,
                            int n4, int B, int M, int nNormBlocks) {
  if ((int)blockIdx.x >= nNormBlocks) {        // tail blocks: full-buffer copy
    int i = ((int)blockIdx.x - nNormBlocks) * 256 + threadIdx.x;
    if (i < n4) out4[i] = mind4[i];
    return;
  }
  int wv = threadIdx.x >> 6;
  int lane = threadIdx.x & 63;
  int row = blockIdx.x * 4 + wv;
  const float* src;
  float* dst;
  char* bdst;
  bool isY;
  if (row < M) {
    isY = true;
    src = y + (size_t)row * DIMS; dst = y2 + row; bdst = yb + (size_t)row * DEXT;
  } else {
    int r = row - M;
    if (r >= B) return;
    isY = false;
    src = x + (size_t)r * DIMS; dst = x2 + r; bdst = xb + (size_t)r * DEXT;
  }
  const float g = isY ? -1.f : 1.f;            // store -y; x(-2) via MX scale
  float s = 0.f;
  #pragma unroll
  for (int h = 0; h < 2; ++h) {
    int c = h * 64 + lane;                     // chunk of 8 k
    const float4* fp = (const float4*)(src + c * 8);
    float4 a0 = fp[0], a1 = fp[1];
    s = fmaf(a0.x, a0.x, s); s = fmaf(a0.y, a0.y, s);
    s = fmaf(a0.z, a0.z, s); s = fmaf(a0.w, a0.w, s);
    s = fmaf(a1.x, a1.x, s); s = fmaf(a1.y, a1.y, s);
    s = fmaf(a1.z, a1.z, s); s = fmaf(a1.w, a1.w, s);
    if (PRE) {
      unsigned w = q4(g * a0.x)        | (q4(g * a0.y) << 4)  |
                   (q4(g * a0.z) << 8) | (q4(g * a0.w) << 12) |
                   (q4(g * a1.x) << 16)| (q4(g * a1.y) << 20) |
                   (q4(g * a1.z) << 24)| (q4(g * a1.w) << 28);
      *(unsigned*)(bdst + c * 4) = w;          // linear k, 4B per 8-elem chunk
    }
  }
  #pragma unroll
  for (int off = 32; off; off >>= 1) s += __shfl_xor(s, off);
  if (lane == 0) *dst = s;
}

// ---------------- phase A: MX-fp4 K=128 MFMA 128x128, dbuf, 4 blocks/CU ----
// grid 1024 (rowblk=bid>>6, colchunk=bid&63); 256 thr = 4 waves 2x2, wave 64x64.
// 8 fp4 tiles (16KB each: A 8KB + B 8KB) double-buffered in 32KB LDS with
// counted vmcnt (stage t+1 in flight while computing t; never drain to 0
// mid-loop). Fully unrolled K-loop (compile-time buffers + folded offsets).
// Epilogue adds exact f32 norms; topk stored [B][nch][8] for coalesced phaseB.
template<bool PRE>
__global__ __launch_bounds__(256, 4) void knn_mx4(
    const float* __restrict__ xf, const float* __restrict__ yf,
    const char* __restrict__ xb, const char* __restrict__ yb,
    const float* __restrict__ x2, const float* __restrict__ y2,
    float* __restrict__ topk_out,           // [B][nch][8] squared dists
    const int* __restrict__ xsp, const int* __restrict__ ysp,
    int B, int M, int nch) {
  __shared__ __align__(16) char smem[32768]; // 2 x (A 8KB + B 8KB); 4KB reuse
  const int tid = threadIdx.x;
  const int wv = tid >> 6, l = tid & 63;
  const int wr = wv >> 1, wc = wv & 1;
  const int g4 = l >> 4, l16 = l & 15;
  const int rowblk = blockIdx.x >> 6, colchunk = blockIdx.x & 63;
  const int r0 = rowblk * BM, c0 = colchunk * BN;
  const int xs = *xsp, ys = *ysp;
  const float FINF = __builtin_inff();

  f32x4 acc[4][4];
  #pragma unroll
  for (int mi = 0; mi < 4; ++mi)
    #pragma unroll
    for (int ni = 0; ni < 4; ++ni)
      acc[mi][ni] = (f32x4){0.f, 0.f, 0.f, 0.f};

  // fp4 pair-line LDS layout per tile (8KB = 64 lines x 128B):
  // line = row>>1; slot = ((q ^ (line&3))<<1) | (row&1)  -> 2-way banks (free)
  auto STAGE1 = [&](char* base, int t) {       // one tile pair: 4 gload/thread
    #pragma unroll
    for (int p = 0; p < 2; ++p) {
      int line = p * 32 + (tid >> 3);
      int slot = tid & 7;
      int r = line * 2 + (slot & 1);
      int q = (slot >> 1) ^ (line & 3);        // pre-inverse-swizzled source
      gload_lds16(xb + (size_t)(r0 + r) * DEXT + t * 64 + q * 16,
                  base + p * 4096 + tid * 16);
    }
    #pragma unroll
    for (int p = 0; p < 2; ++p) {
      int line = p * 32 + (tid >> 3);
      int slot = tid & 7;
      int r = line * 2 + (slot & 1);
      int q = (slot >> 1) ^ (line & 3);
      gload_lds16(yb + (size_t)(c0 + r) * DEXT + t * 64 + q * 16,
                  base + 8192 + p * 4096 + tid * 16);
    }
  };

  auto LDFRAG4 = [&](const char* base, int row) -> i32x8 {   // 16B fp4 frag
    int line = row >> 1;
    int slot = ((g4 ^ (line & 3)) << 1) | (row & 1);
    i32x4 v = *(const i32x4*)(base + line * 128 + slot * 16);
    i32x8 r;
    r[0] = v[0]; r[1] = v[1]; r[2] = v[2]; r[3] = v[3];
    r[4] = 0; r[5] = 0; r[6] = 0; r[7] = 0;
    return r;
  };
  auto LDFRAG8 = [&](const char* base, int row) -> i32x8 {   // 32B fp8 frag
    i32x4 lo = *(const i32x4*)(base + row * 128 + (((g4 * 2 + 0) ^ (row & 7)) * 16));
    i32x4 hi = *(const i32x4*)(base + row * 128 + (((g4 * 2 + 1) ^ (row & 7)) * 16));
    i32x8 v;
    v[0] = lo[0]; v[1] = lo[1]; v[2] = lo[2]; v[3] = lo[3];
    v[4] = hi[0]; v[5] = hi[1]; v[6] = hi[2]; v[7] = hi[3];
    return v;
  };

  auto COMPUTE1 = [&](const char* base) {      // one fp4 tile (K=128)
    const char* bb = base + 8192;
    i32x8 bf[4];
    #pragma unroll
    for (int ni = 0; ni < 4; ++ni)
      bf[ni] = LDFRAG4(bb, wc * 64 + ni * 16 + l16);
    #pragma unroll
    for (int mi = 0; mi < 4; ++mi) {
      i32x8 a = LDFRAG4(base, wr * 64 + mi * 16 + l16);
      #pragma unroll
      for (int ni = 0; ni < 4; ++ni)           // swapped: C[ycol][xrow]
        acc[mi][ni] = __builtin_amdgcn_mfma_scale_f32_16x16x128_f8f6f4(
            bf[ni], a, acc[mi][ni], 4, 4, 0, SCL2, 0, SCL1);  // fp4; (-y)*2
    }
  };
  auto STAGE_CONV = [&](int t) {               // fallback: f32 -> fp8 in-reg
    #pragma unroll
    for (int p = 0; p < 4; ++p) {
      int row = p * 32 + (tid >> 3);
      int s = (tid & 7) ^ (row & 7);
      {
        const float* g0 = xf + (size_t)(r0 + row) * DIMS + t * 128 + s * 16;
        float4 a0 = *(const float4*)g0, a1 = *(const float4*)(g0 + 4);
        float4 a2 = *(const float4*)(g0 + 8), a3 = *(const float4*)(g0 + 12);
        int w0 = CVT(a0.x, a0.y, 0, 0); w0 = CVT(a0.z, a0.w, w0, 1);
        int w1 = CVT(a1.x, a1.y, 0, 0); w1 = CVT(a1.z, a1.w, w1, 1);
        int w2 = CVT(a2.x, a2.y, 0, 0); w2 = CVT(a2.z, a2.w, w2, 1);
        int w3 = CVT(a3.x, a3.y, 0, 0); w3 = CVT(a3.z, a3.w, w3, 1);
        *(int4*)(smem + p * 4096 + tid * 16) = make_int4(w0, w1, w2, w3);
      }
      {
        const float* g0 = yf + (size_t)(c0 + row) * DIMS + t * 128 + s * 16;
        float4 a0 = *(const float4*)g0, a1 = *(const float4*)(g0 + 4);
        float4 a2 = *(const float4*)(g0 + 8), a3 = *(const float4*)(g0 + 12);
        int w0 = CVT(a0.x, a0.y, 0, 0); w0 = CVT(a0.z, a0.w, w0, 1);
        int w1 = CVT(a1.x, a1.y, 0, 0); w1 = CVT(a1.z, a1.w, w1, 1);
        int w2 = CVT(a2.x, a2.y, 0, 0); w2 = CVT(a2.z, a2.w, w2, 1);
        int w3 = CVT(a3.x, a3.y, 0, 0); w3 = CVT(a3.z, a3.w, w3, 1);
        *(int4*)(smem + 16384 + p * 4096 + tid * 16) = make_int4(w0, w1, w2, w3);
      }
    }
  };

  if (PRE) {
    STAGE1(smem, 0);                           // prologue: tile 0 in flight
    #pragma unroll
    for (int t = 0; t < 8; ++t) {              // fully unrolled: static buffers
      char* cb = smem + (t & 1) * 16384;
      char* nb = smem + ((t + 1) & 1) * 16384;
      if (t + 1 < 8) {
        STAGE1(nb, t + 1);                     // 4 loads -> other buffer (its
                                               //  readers finished at t-1 bar)
        asm volatile("s_waitcnt vmcnt(4)" ::: "memory");  // tile t landed only
      } else {
        asm volatile("s_waitcnt vmcnt(0)" ::: "memory");
      }
      asm volatile("s_barrier" ::: "memory");  // tile t visible to all waves
      COMPUTE1(cb);
      asm volatile("s_barrier" ::: "memory");  // all waves done reading tile t
    }
  } else {
    #pragma unroll 1
    for (int t = 0; t < DIMS / 128; ++t) {
      __syncthreads();
      STAGE_CONV(t);
      __syncthreads();
      // fp8 tile, unit scales: acc accumulates x.y (note: NOT -2x.y)
      i32x8 bf[4];
      #pragma unroll
      for (int ni = 0; ni < 4; ++ni)
        bf[ni] = LDFRAG8(smem + 16384, wc * 64 + ni * 16 + l16);
      #pragma unroll
      for (int mi = 0; mi < 4; ++mi) {
        i32x8 a = LDFRAG8(smem, wr * 64 + mi * 16 + l16);
        #pragma unroll
        for (int ni = 0; ni < 4; ++ni)
          acc[mi][ni] = __builtin_amdgcn_mfma_scale_f32_16x16x128_f8f6f4(
              bf[ni], a, acc[mi][ni], 0, 0, 0, SCL1, 0, SCL1);
      }
    }
  }

  // ---- epilogue: per-lane in-register top-8; exact f32 norms added here ---
  const int cb2 = c0 + wc * 64 + g4 * 4;
  float y2v[16];
  #pragma unroll
  for (int ni = 0; ni < 4; ++ni)
    #pragma unroll
    for (int j = 0; j < 4; ++j)
      y2v[ni * 4 + j] = y2[cb2 + ni * 16 + j];

  float t8[4][8];
  #pragma unroll
  for (int mi = 0; mi < 4; ++mi) {
    const int gr = r0 + wr * 64 + mi * 16 + l16;
    const int dmi = xs + gr - ys - cb2;        // equals ni*16+j iff self-pair
    const float xv = x2[gr];
    float a[8], b[8];
    #pragma unroll
    for (int ni = 0; ni < 2; ++ni)
      #pragma unroll
      for (int j = 0; j < 4; ++j) {
        float sq = PRE ? fmaxf(xv + y2v[ni * 4 + j] + acc[mi][ni][j], 0.f)
                       : fmaxf(xv + y2v[ni * 4 + j] - 2.f * acc[mi][ni][j], 0.f);
        if (dmi == ni * 16 + j) sq = FINF;
        a[ni * 4 + j] = sq;
      }
    #pragma unroll
    for (int ni = 2; ni < 4; ++ni)
      #pragma unroll
      for (int j = 0; j < 4; ++j) {
        float sq = PRE ? fmaxf(xv + y2v[ni * 4 + j] + acc[mi][ni][j], 0.f)
                       : fmaxf(xv + y2v[ni * 4 + j] - 2.f * acc[mi][ni][j], 0.f);
        if (dmi == ni * 16 + j) sq = FINF;
        b[(ni - 2) * 4 + j] = sq;
      }
    sort8(a); sort8(b); merge8(a, b);          // top8 of lane's 16, ascending
    #pragma unroll
    for (int k = 0; k < 8; ++k) b[k] = __shfl_xor(a[k], 16);
    merge8(a, b);
    #pragma unroll
    for (int k = 0; k < 8; ++k) b[k] = __shfl_xor(a[k], 32);
    merge8(a, b);                              // all 4 g4 groups merged
    #pragma unroll
    for (int k = 0; k < 8; ++k) t8[mi][k] = a[k];
  }

  float* xbuf = (float*)smem;                  // 4KB hop to merge wc strips
  __syncthreads();
  if (wc == 1 && g4 == 0) {
    #pragma unroll
    for (int mi = 0; mi < 4; ++mi) {
      float* p = xbuf + ((wr * 4 + mi) * 16 + l16) * 8;
      *(f32x4*)p       = (f32x4){t8[mi][0], t8[mi][1], t8[mi][2], t8[mi][3]};
      *((f32x4*)p + 1) = (f32x4){t8[mi][4], t8[mi][5], t8[mi][6], t8[mi][7]};
    }
  }
  __syncthreads();
  if (wc == 0 && g4 == 0) {
    #pragma unroll
    for (int mi = 0; mi < 4; ++mi) {
      const float* p = xbuf + ((wr * 4 + mi) * 16 + l16) * 8;
      float b[8];
      #pragma unroll
      for (int k = 0; k < 8; ++k) b[k] = p[k];
      merge8(t8[mi], b);
      int gr = r0 + wr * 64 + mi * 16 + l16;
      float* o = topk_out + ((size_t)gr * nch + colchunk) * 8;  // [B][nch][8]
      *(f32x4*)o       = (f32x4){t8[mi][0], t8[mi][1], t8[mi][2], t8[mi][3]};
      *((f32x4*)o + 1) = (f32x4){t8[mi][4], t8[mi][5], t8[mi][6], t8[mi][7]};
    }
  }
}

// ---------------- phase B: wave-per-row merge of nch sorted lists ----------
// topk is [B][nch][8]: lane = chunk reads 32B contiguous -> wave reads one
// coalesced 2KB row.
__global__ void knn_phaseB(const float* __restrict__ topk,
                           const float* __restrict__ mind_in,
                           float* __restrict__ out,
                           const int* __restrict__ xsp, int B, int nch) {
  int w = threadIdx.x >> 6, lane = threadIdx.x & 63;
  int r = blockIdx.x * 4 + w;
  if (r >= B) return;
  int x_start = *xsp;
  const float* bp = topk + ((size_t)r * nch + lane) * 8;   // chunk = lane
  float t8[8];
  f32x4 v0 = *(const f32x4*)bp;
  f32x4 v1 = *(const f32x4*)(bp + 4);
  t8[0]=v0[0]; t8[1]=v0[1]; t8[2]=v0[2]; t8[3]=v0[3];
  t8[4]=v1[0]; t8[5]=v1[1]; t8[6]=v1[2]; t8[7]=v1[3];
  #pragma unroll
  for (int off = 32; off >= 1; off >>= 1) {              // butterfly merge
    float b[8];
    #pragma unroll
    for (int k = 0; k < 8; ++k) b[k] = __shfl_xor(t8[k], off);
    merge8(t8, b);
  }
  if (lane == 0) {
    float lst[8];
    #pragma unroll
    for (int k = 0; k < 8; ++k) lst[k] = sqrtf(t8[k]);   // squared -> distance
    float cur[8];
    const float* cp = mind_in + (size_t)(x_start + r) * KNN_K;
    #pragma unroll
    for (int k = 0; k < 8; ++k) cur[k] = cp[k];
    sort8(cur);
    merge8(lst, cur);
    #pragma unroll
    for (int k = 0; k < 8; ++k) out[(size_t)(x_start + r) * KNN_K + k] = lst[k];
  }
}

extern "C" void kernel_launch(void* const* d_in, const int* in_sizes, int n_in,
                              void* d_out, int out_size, void* d_ws, size_t ws_size,
                              hipStream_t stream) {
  const float* x = (const float*)d_in[0];
  const float* y = (const float*)d_in[1];
  const float* mind = (const float*)d_in[2];
  const int* xsp = (const int*)d_in[3];
  const int* ysp = (const int*)d_in[4];
  float* out = (float*)d_out;

  const int B = in_sizes[0] / DIMS;       // 2048
  const int M = in_sizes[1] / DIMS;       // 8192
  const int nch = M / BN;                 // 64

  float* y2 = (float*)d_ws;               // [M]
  float* x2 = y2 + M;                     // [B]
  float* topk = x2 + B;                   // [B][nch][8]
  size_t base = ((size_t)(M + B) + (size_t)B * nch * 8) * 4;
  base = (base + 255) & ~(size_t)255;
  char* xbw = (char*)d_ws + base;
  char* ybw = xbw + (size_t)B * DEXT;
  size_t need = base + ((size_t)B + (size_t)M) * DEXT;
  bool pre = ws_size >= need;

  int nNorm = (B + M + 3) / 4;
  int n4 = out_size / 4;
  int nCopy = (n4 + 255) / 256;
  if (pre)
    prep_kernel<true><<<nNorm + nCopy, 256, 0, stream>>>(
        x, y, x2, y2, xbw, ybw, (const float4*)mind, (float4*)out, n4, B, M, nNorm);
  else
    prep_kernel<false><<<nNorm + nCopy, 256, 0, stream>>>(
        x, y, x2, y2, xbw, ybw, (const float4*)mind, (float4*)out, n4, B, M, nNorm);

  int nBlocks = (B / BM) * nch;           // 16 x 64 = 1024 (4 blocks/CU)
  if (pre)
    knn_mx4<true><<<nBlocks, 256, 0, stream>>>(x, y, xbw, ybw, x2, y2, topk, xsp, ysp, B, M, nch);
  else
    knn_mx4<false><<<nBlocks, 256, 0, stream>>>(x, y, xbw, ybw, x2, y2, topk, xsp, ysp, B, M, nch);

  knn_phaseB<<<(B + 3) / 4, 256, 0, stream>>>(topk, mind, out, xsp, B, nch);
}

// Round 17
// 40.613 us; speedup vs baseline: 1.0066x; 1.0066x over previous
//
#include <hip/hip_runtime.h>

#define DIMS 1024
#define DEXT 512         // bytes/row: 512 fp4 data (norms handled in epilogue)
#define KNN_K 8
#define BM 128
#define BN 128

typedef float f32x4 __attribute__((ext_vector_type(4)));
typedef int i32x4 __attribute__((ext_vector_type(4)));
typedef int i32x8 __attribute__((ext_vector_type(8)));

#define CVT(a, b, old, w) __builtin_amdgcn_cvt_pk_fp8_f32((a), (b), (old), (w))
#define SCL1 0x7f7f7f7f  // E8M0 127 -> x1
#define SCL2 0x80808080  // E8M0 128 -> x2 (folds the -2 into -y's scale)

// compare-exchange (ascending)
__device__ __forceinline__ void ce(float& a, float& b) {
  float lo = fminf(a, b), hi = fmaxf(a, b); a = lo; b = hi;
}
// Batcher odd-even merge sort, 8 elements ascending (19 CE, branch-free)
__device__ __forceinline__ void sort8(float (&v)[8]) {
  ce(v[0],v[1]); ce(v[2],v[3]); ce(v[4],v[5]); ce(v[6],v[7]);
  ce(v[0],v[2]); ce(v[1],v[3]); ce(v[4],v[6]); ce(v[5],v[7]);
  ce(v[1],v[2]); ce(v[5],v[6]);
  ce(v[0],v[4]); ce(v[1],v[5]); ce(v[2],v[6]); ce(v[3],v[7]);
  ce(v[2],v[4]); ce(v[3],v[5]);
  ce(v[1],v[2]); ce(v[3],v[4]); ce(v[5],v[6]);
}
// a,b ascending sorted-8 -> a = smallest 8 of union, ascending
__device__ __forceinline__ void merge8(float (&a)[8], const float (&b)[8]) {
  float u[8];
  #pragma unroll
  for (int k = 0; k < 8; ++k) u[k] = fminf(a[k], b[7 - k]);  // bitonic
  ce(u[0],u[4]); ce(u[1],u[5]); ce(u[2],u[6]); ce(u[3],u[7]);
  ce(u[0],u[2]); ce(u[1],u[3]); ce(u[4],u[6]); ce(u[5],u[7]);
  ce(u[0],u[1]); ce(u[2],u[3]); ce(u[4],u[5]); ce(u[6],u[7]);
  #pragma unroll
  for (int k = 0; k < 8; ++k) a[k] = u[k];
}

__device__ __forceinline__ void gload_lds16(const void* g, void* l) {
  __builtin_amdgcn_global_load_lds(
      (const __attribute__((address_space(1))) void*)g,
      (__attribute__((address_space(3))) void*)l, 16, 0, 0);
}

// e2m1 quantize (round-to-nearest): {0,.5,1,1.5,2,3,4,6} + sign
__device__ __forceinline__ unsigned q4(float v) {
  float a = fabsf(v);
  unsigned code = (a >= 0.25f) + (a >= 0.75f) + (a >= 1.25f) + (a >= 1.75f)
                + (a >= 2.5f) + (a >= 3.5f) + (a >= 5.f);
  return (v < 0.f ? 8u : 0u) | code;
}

// ---- prep: norms + fp4 pack (x, -y) + min_dists->out copy ------------------
// Data MFMA uses scale 2 on the (-y) operand => acc = -2 x.y; epilogue adds
// exact f32 x2[r] + y2[c] => squared distance.
template<bool PRE>
__global__ void prep_kernel(const float* __restrict__ x, const float* __restrict__ y,
                            float* __restrict__ x2, float* __restrict__ y2,
                            char* __restrict__ xb, char* __restrict__ yb,
                            const float4* __restrict__ mind4, float4* __restrict__ out4,
                            int n4, int B, int M, int nNormBlocks) {
  if ((int)blockIdx.x >= nNormBlocks) {        // tail blocks: full-buffer copy
    int i = ((int)blockIdx.x - nNormBlocks) * 256 + threadIdx.x;
    if (i < n4) out4[i] = mind4[i];
    return;
  }
  int wv = threadIdx.x >> 6;
  int lane = threadIdx.x & 63;
  int row = blockIdx.x * 4 + wv;
  const float* src;
  float* dst;
  char* bdst;
  bool isY;
  if (row < M) {
    isY = true;
    src = y + (size_t)row * DIMS; dst = y2 + row; bdst = yb + (size_t)row * DEXT;
  } else {
    int r = row - M;
    if (r >= B) return;
    isY = false;
    src = x + (size_t)r * DIMS; dst = x2 + r; bdst = xb + (size_t)r * DEXT;
  }
  const float g = isY ? -1.f : 1.f;            // store -y; x(-2) via MX scale
  float s = 0.f;
  #pragma unroll
  for (int h = 0; h < 2; ++h) {
    int c = h * 64 + lane;                     // chunk of 8 k
    const float4* fp = (const float4*)(src + c * 8);
    float4 a0 = fp[0], a1 = fp[1];
    s = fmaf(a0.x, a0.x, s); s = fmaf(a0.y, a0.y, s);
    s = fmaf(a0.z, a0.z, s); s = fmaf(a0.w, a0.w, s);
    s = fmaf(a1.x, a1.x, s); s = fmaf(a1.y, a1.y, s);
    s = fmaf(a1.z, a1.z, s); s = fmaf(a1.w, a1.w, s);
    if (PRE) {
      unsigned w = q4(g * a0.x)        | (q4(g * a0.y) << 4)  |
                   (q4(g * a0.z) << 8) | (q4(g * a0.w) << 12) |
                   (q4(g * a1.x) << 16)| (q4(g * a1.y) << 20) |
                   (q4(g * a1.z) << 24)| (q4(g * a1.w) << 28);
      *(unsigned*)(bdst + c * 4) = w;          // linear k, 4B per 8-elem chunk
    }
  }
  #pragma unroll
  for (int off = 32; off; off >>= 1) s += __shfl_xor(s, off);
  if (lane == 0) *dst = s;
}

// ---------------- phase A: MX-fp4 K=128 MFMA 128x128, dbuf, 4 blocks/CU ----
// grid 1024 (rowblk=bid>>6, colchunk=bid&63); 256 thr = 4 waves 2x2, wave 64x64.
// 8 fp4 tiles double-buffered with counted vmcnt. Epilogue: per-lane sorted
// top-8 of each 64-col wave strip, written DIRECTLY as chunk colchunk*2+wc
// (no wc-merge, no LDS hop, no extra barriers). topk = [B][128][8].
template<bool PRE>
__global__ __launch_bounds__(256, 4) void knn_mx4(
    const float* __restrict__ xf, const float* __restrict__ yf,
    const char* __restrict__ xb, const char* __restrict__ yb,
    const float* __restrict__ x2, const float* __restrict__ y2,
    float* __restrict__ topk_out,           // [B][128][8] squared dists
    const int* __restrict__ xsp, const int* __restrict__ ysp,
    int B, int M, int nch) {
  __shared__ __align__(16) char smem[32768]; // 2 x (A 8KB + B 8KB)
  const int tid = threadIdx.x;
  const int wv = tid >> 6, l = tid & 63;
  const int wr = wv >> 1, wc = wv & 1;
  const int g4 = l >> 4, l16 = l & 15;
  const int rowblk = blockIdx.x >> 6, colchunk = blockIdx.x & 63;
  const int r0 = rowblk * BM, c0 = colchunk * BN;
  const int xs = *xsp, ys = *ysp;
  const float FINF = __builtin_inff();

  f32x4 acc[4][4];
  #pragma unroll
  for (int mi = 0; mi < 4; ++mi)
    #pragma unroll
    for (int ni = 0; ni < 4; ++ni)
      acc[mi][ni] = (f32x4){0.f, 0.f, 0.f, 0.f};

  // fp4 pair-line LDS layout per tile (8KB = 64 lines x 128B):
  // line = row>>1; slot = ((q ^ (line&3))<<1) | (row&1)  -> 2-way banks (free)
  auto STAGE1 = [&](char* base, int t) {       // one tile pair: 4 gload/thread
    #pragma unroll
    for (int p = 0; p < 2; ++p) {
      int line = p * 32 + (tid >> 3);
      int slot = tid & 7;
      int r = line * 2 + (slot & 1);
      int q = (slot >> 1) ^ (line & 3);        // pre-inverse-swizzled source
      gload_lds16(xb + (size_t)(r0 + r) * DEXT + t * 64 + q * 16,
                  base + p * 4096 + tid * 16);
    }
    #pragma unroll
    for (int p = 0; p < 2; ++p) {
      int line = p * 32 + (tid >> 3);
      int slot = tid & 7;
      int r = line * 2 + (slot & 1);
      int q = (slot >> 1) ^ (line & 3);
      gload_lds16(yb + (size_t)(c0 + r) * DEXT + t * 64 + q * 16,
                  base + 8192 + p * 4096 + tid * 16);
    }
  };

  auto LDFRAG4 = [&](const char* base, int row) -> i32x8 {   // 16B fp4 frag
    int line = row >> 1;
    int slot = ((g4 ^ (line & 3)) << 1) | (row & 1);
    i32x4 v = *(const i32x4*)(base + line * 128 + slot * 16);
    i32x8 r;
    r[0] = v[0]; r[1] = v[1]; r[2] = v[2]; r[3] = v[3];
    r[4] = 0; r[5] = 0; r[6] = 0; r[7] = 0;
    return r;
  };
  auto LDFRAG8 = [&](const char* base, int row) -> i32x8 {   // 32B fp8 frag
    i32x4 lo = *(const i32x4*)(base + row * 128 + (((g4 * 2 + 0) ^ (row & 7)) * 16));
    i32x4 hi = *(const i32x4*)(base + row * 128 + (((g4 * 2 + 1) ^ (row & 7)) * 16));
    i32x8 v;
    v[0] = lo[0]; v[1] = lo[1]; v[2] = lo[2]; v[3] = lo[3];
    v[4] = hi[0]; v[5] = hi[1]; v[6] = hi[2]; v[7] = hi[3];
    return v;
  };

  auto COMPUTE1 = [&](const char* base) {      // one fp4 tile (K=128)
    const char* bb = base + 8192;
    i32x8 bf[4];
    #pragma unroll
    for (int ni = 0; ni < 4; ++ni)
      bf[ni] = LDFRAG4(bb, wc * 64 + ni * 16 + l16);
    #pragma unroll
    for (int mi = 0; mi < 4; ++mi) {
      i32x8 a = LDFRAG4(base, wr * 64 + mi * 16 + l16);
      #pragma unroll
      for (int ni = 0; ni < 4; ++ni)           // swapped: C[ycol][xrow]
        acc[mi][ni] = __builtin_amdgcn_mfma_scale_f32_16x16x128_f8f6f4(
            bf[ni], a, acc[mi][ni], 4, 4, 0, SCL2, 0, SCL1);  // fp4; (-y)*2
    }
  };
  auto STAGE_CONV = [&](int t) {               // fallback: f32 -> fp8 in-reg
    #pragma unroll
    for (int p = 0; p < 4; ++p) {
      int row = p * 32 + (tid >> 3);
      int s = (tid & 7) ^ (row & 7);
      {
        const float* g0 = xf + (size_t)(r0 + row) * DIMS + t * 128 + s * 16;
        float4 a0 = *(const float4*)g0, a1 = *(const float4*)(g0 + 4);
        float4 a2 = *(const float4*)(g0 + 8), a3 = *(const float4*)(g0 + 12);
        int w0 = CVT(a0.x, a0.y, 0, 0); w0 = CVT(a0.z, a0.w, w0, 1);
        int w1 = CVT(a1.x, a1.y, 0, 0); w1 = CVT(a1.z, a1.w, w1, 1);
        int w2 = CVT(a2.x, a2.y, 0, 0); w2 = CVT(a2.z, a2.w, w2, 1);
        int w3 = CVT(a3.x, a3.y, 0, 0); w3 = CVT(a3.z, a3.w, w3, 1);
        *(int4*)(smem + p * 4096 + tid * 16) = make_int4(w0, w1, w2, w3);
      }
      {
        const float* g0 = yf + (size_t)(c0 + row) * DIMS + t * 128 + s * 16;
        float4 a0 = *(const float4*)g0, a1 = *(const float4*)(g0 + 4);
        float4 a2 = *(const float4*)(g0 + 8), a3 = *(const float4*)(g0 + 12);
        int w0 = CVT(a0.x, a0.y, 0, 0); w0 = CVT(a0.z, a0.w, w0, 1);
        int w1 = CVT(a1.x, a1.y, 0, 0); w1 = CVT(a1.z, a1.w, w1, 1);
        int w2 = CVT(a2.x, a2.y, 0, 0); w2 = CVT(a2.z, a2.w, w2, 1);
        int w3 = CVT(a3.x, a3.y, 0, 0); w3 = CVT(a3.z, a3.w, w3, 1);
        *(int4*)(smem + 16384 + p * 4096 + tid * 16) = make_int4(w0, w1, w2, w3);
      }
    }
  };

  if (PRE) {
    STAGE1(smem, 0);                           // prologue: tile 0 in flight
    #pragma unroll 1
    for (int t = 0; t < 8; ++t) {
      char* cb = smem + (t & 1) * 16384;
      char* nb = smem + ((t + 1) & 1) * 16384;
      if (t + 1 < 8) {
        STAGE1(nb, t + 1);                     // 4 loads -> other buffer (its
                                               //  readers finished at t-1 bar)
        asm volatile("s_waitcnt vmcnt(4)" ::: "memory");  // tile t landed only
      } else {
        asm volatile("s_waitcnt vmcnt(0)" ::: "memory");
      }
      asm volatile("s_barrier" ::: "memory");  // tile t visible to all waves
      COMPUTE1(cb);
      asm volatile("s_barrier" ::: "memory");  // all waves done reading tile t
    }
  } else {
    #pragma unroll 1
    for (int t = 0; t < DIMS / 128; ++t) {
      __syncthreads();
      STAGE_CONV(t);
      __syncthreads();
      // fp8 tile, unit scales: acc accumulates x.y (note: NOT -2x.y)
      i32x8 bf[4];
      #pragma unroll
      for (int ni = 0; ni < 4; ++ni)
        bf[ni] = LDFRAG8(smem + 16384, wc * 64 + ni * 16 + l16);
      #pragma unroll
      for (int mi = 0; mi < 4; ++mi) {
        i32x8 a = LDFRAG8(smem, wr * 64 + mi * 16 + l16);
        #pragma unroll
        for (int ni = 0; ni < 4; ++ni)
          acc[mi][ni] = __builtin_amdgcn_mfma_scale_f32_16x16x128_f8f6f4(
              bf[ni], a, acc[mi][ni], 0, 0, 0, SCL1, 0, SCL1);
      }
    }
  }

  // ---- epilogue: per-lane top-8 of this wave's 64-col strip; direct store --
  const int cb2 = c0 + wc * 64 + g4 * 4;
  float y2v[16];
  #pragma unroll
  for (int ni = 0; ni < 4; ++ni)
    #pragma unroll
    for (int j = 0; j < 4; ++j)
      y2v[ni * 4 + j] = y2[cb2 + ni * 16 + j];

  #pragma unroll
  for (int mi = 0; mi < 4; ++mi) {
    const int gr = r0 + wr * 64 + mi * 16 + l16;
    const int dmi = xs + gr - ys - cb2;        // equals ni*16+j iff self-pair
    const float xv = x2[gr];
    float a[8], b[8];
    #pragma unroll
    for (int ni = 0; ni < 2; ++ni)
      #pragma unroll
      for (int j = 0; j < 4; ++j) {
        float sq = PRE ? fmaxf(xv + y2v[ni * 4 + j] + acc[mi][ni][j], 0.f)
                       : fmaxf(xv + y2v[ni * 4 + j] - 2.f * acc[mi][ni][j], 0.f);
        if (dmi == ni * 16 + j) sq = FINF;
        a[ni * 4 + j] = sq;
      }
    #pragma unroll
    for (int ni = 2; ni < 4; ++ni)
      #pragma unroll
      for (int j = 0; j < 4; ++j) {
        float sq = PRE ? fmaxf(xv + y2v[ni * 4 + j] + acc[mi][ni][j], 0.f)
                       : fmaxf(xv + y2v[ni * 4 + j] - 2.f * acc[mi][ni][j], 0.f);
        if (dmi == ni * 16 + j) sq = FINF;
        b[(ni - 2) * 4 + j] = sq;
      }
    sort8(a); sort8(b); merge8(a, b);          // top8 of lane's 16, ascending
    #pragma unroll
    for (int k = 0; k < 8; ++k) b[k] = __shfl_xor(a[k], 16);
    merge8(a, b);
    #pragma unroll
    for (int k = 0; k < 8; ++k) b[k] = __shfl_xor(a[k], 32);
    merge8(a, b);                              // top8 of the strip's 64 cols
    if (g4 == 0) {                             // one writer per row per strip
      float* o = topk_out + ((size_t)gr * nch + (colchunk * 2 + wc)) * 8;
      *(f32x4*)o       = (f32x4){a[0], a[1], a[2], a[3]};
      *((f32x4*)o + 1) = (f32x4){a[4], a[5], a[6], a[7]};
    }
  }
}

// ---------------- phase B: wave-per-row merge of nch=128 sorted lists ------
// topk is [B][128][8]: lane reads chunks lane and lane+64 (coalesced 2KB x2).
__global__ void knn_phaseB(const float* __restrict__ topk,
                           const float* __restrict__ mind_in,
                           float* __restrict__ out,
                           const int* __restrict__ xsp, int B, int nch) {
  int w = threadIdx.x >> 6, lane = threadIdx.x & 63;
  int r = blockIdx.x * 4 + w;
  if (r >= B) return;
  int x_start = *xsp;
  const float* bp = topk + ((size_t)r * nch + lane) * 8;
  const float* bq = topk + ((size_t)r * nch + lane + 64) * 8;
  float t8[8], u8[8];
  f32x4 v0 = *(const f32x4*)bp, v1 = *(const f32x4*)(bp + 4);
  f32x4 w0 = *(const f32x4*)bq, w1 = *(const f32x4*)(bq + 4);
  t8[0]=v0[0]; t8[1]=v0[1]; t8[2]=v0[2]; t8[3]=v0[3];
  t8[4]=v1[0]; t8[5]=v1[1]; t8[6]=v1[2]; t8[7]=v1[3];
  u8[0]=w0[0]; u8[1]=w0[1]; u8[2]=w0[2]; u8[3]=w0[3];
  u8[4]=w1[0]; u8[5]=w1[1]; u8[6]=w1[2]; u8[7]=w1[3];
  merge8(t8, u8);                              // both ascending already
  #pragma unroll
  for (int off = 32; off >= 1; off >>= 1) {    // butterfly merge
    float b[8];
    #pragma unroll
    for (int k = 0; k < 8; ++k) b[k] = __shfl_xor(t8[k], off);
    merge8(t8, b);
  }
  if (lane == 0) {
    float lst[8];
    #pragma unroll
    for (int k = 0; k < 8; ++k) lst[k] = sqrtf(t8[k]);   // squared -> distance
    float cur[8];
    const float* cp = mind_in + (size_t)(x_start + r) * KNN_K;
    #pragma unroll
    for (int k = 0; k < 8; ++k) cur[k] = cp[k];
    sort8(cur);
    merge8(lst, cur);
    #pragma unroll
    for (int k = 0; k < 8; ++k) out[(size_t)(x_start + r) * KNN_K + k] = lst[k];
  }
}

extern "C" void kernel_launch(void* const* d_in, const int* in_sizes, int n_in,
                              void* d_out, int out_size, void* d_ws, size_t ws_size,
                              hipStream_t stream) {
  const float* x = (const float*)d_in[0];
  const float* y = (const float*)d_in[1];
  const float* mind = (const float*)d_in[2];
  const int* xsp = (const int*)d_in[3];
  const int* ysp = (const int*)d_in[4];
  float* out = (float*)d_out;

  const int B = in_sizes[0] / DIMS;       // 2048
  const int M = in_sizes[1] / DIMS;       // 8192
  const int nch = M / 64;                 // 128 strips of 64 cols

  float* y2 = (float*)d_ws;               // [M]
  float* x2 = y2 + M;                     // [B]
  float* topk = x2 + B;                   // [B][nch][8]
  size_t base = ((size_t)(M + B) + (size_t)B * nch * 8) * 4;
  base = (base + 255) & ~(size_t)255;
  char* xbw = (char*)d_ws + base;
  char* ybw = xbw + (size_t)B * DEXT;
  size_t need = base + ((size_t)B + (size_t)M) * DEXT;
  bool pre = ws_size >= need;

  int nNorm = (B + M + 3) / 4;
  int n4 = out_size / 4;
  int nCopy = (n4 + 255) / 256;
  if (pre)
    prep_kernel<true><<<nNorm + nCopy, 256, 0, stream>>>(
        x, y, x2, y2, xbw, ybw, (const float4*)mind, (float4*)out, n4, B, M, nNorm);
  else
    prep_kernel<false><<<nNorm + nCopy, 256, 0, stream>>>(
        x, y, x2, y2, xbw, ybw, (const float4*)mind, (float4*)out, n4, B, M, nNorm);

  int nBlocks = (B / BM) * (M / BN);      // 16 x 64 = 1024 (4 blocks/CU)
  if (pre)
    knn_mx4<true><<<nBlocks, 256, 0, stream>>>(x, y, xbw, ybw, x2, y2, topk, xsp, ysp, B, M, nch);
  else
    knn_mx4<false><<<nBlocks, 256, 0, stream>>>(x, y, xbw, ybw, x2, y2, topk, xsp, ysp, B, M, nch);

  knn_phaseB<<<(B + 3) / 4, 256, 0, stream>>>(topk, mind, out, xsp, B, nch);
}

// Round 18
// 40.337 us; speedup vs baseline: 1.0135x; 1.0068x over previous
//
#include <hip/hip_runtime.h>

#define DIMS 1024
#define DEXT 512         // bytes/row: 512 fp4 data (norms handled in epilogue)
#define KNN_K 8
#define BM 128
#define BN 128

typedef float f32x4 __attribute__((ext_vector_type(4)));
typedef int i32x4 __attribute__((ext_vector_type(4)));
typedef int i32x8 __attribute__((ext_vector_type(8)));

#define CVT(a, b, old, w) __builtin_amdgcn_cvt_pk_fp8_f32((a), (b), (old), (w))
#define SCL1 0x7f7f7f7f  // E8M0 127 -> x1
#define SCL2 0x80808080  // E8M0 128 -> x2 (folds the -2 into -y's scale)

// compare-exchange (ascending)
__device__ __forceinline__ void ce(float& a, float& b) {
  float lo = fminf(a, b), hi = fmaxf(a, b); a = lo; b = hi;
}
// Batcher odd-even merge sort, 8 elements ascending (19 CE, branch-free)
__device__ __forceinline__ void sort8(float (&v)[8]) {
  ce(v[0],v[1]); ce(v[2],v[3]); ce(v[4],v[5]); ce(v[6],v[7]);
  ce(v[0],v[2]); ce(v[1],v[3]); ce(v[4],v[6]); ce(v[5],v[7]);
  ce(v[1],v[2]); ce(v[5],v[6]);
  ce(v[0],v[4]); ce(v[1],v[5]); ce(v[2],v[6]); ce(v[3],v[7]);
  ce(v[2],v[4]); ce(v[3],v[5]);
  ce(v[1],v[2]); ce(v[3],v[4]); ce(v[5],v[6]);
}
// a,b ascending sorted-8 -> a = smallest 8 of union, ascending
__device__ __forceinline__ void merge8(float (&a)[8], const float (&b)[8]) {
  float u[8];
  #pragma unroll
  for (int k = 0; k < 8; ++k) u[k] = fminf(a[k], b[7 - k]);  // bitonic
  ce(u[0],u[4]); ce(u[1],u[5]); ce(u[2],u[6]); ce(u[3],u[7]);
  ce(u[0],u[2]); ce(u[1],u[3]); ce(u[4],u[6]); ce(u[5],u[7]);
  ce(u[0],u[1]); ce(u[2],u[3]); ce(u[4],u[5]); ce(u[6],u[7]);
  #pragma unroll
  for (int k = 0; k < 8; ++k) a[k] = u[k];
}

__device__ __forceinline__ void gload_lds16(const void* g, void* l) {
  __builtin_amdgcn_global_load_lds(
      (const __attribute__((address_space(1))) void*)g,
      (__attribute__((address_space(3))) void*)l, 16, 0, 0);
}

// e2m1 quantize (round-to-nearest): {0,.5,1,1.5,2,3,4,6} + sign
__device__ __forceinline__ unsigned q4(float v) {
  float a = fabsf(v);
  unsigned code = (a >= 0.25f) + (a >= 0.75f) + (a >= 1.25f) + (a >= 1.75f)
                + (a >= 2.5f) + (a >= 3.5f) + (a >= 5.f);
  return (v < 0.f ? 8u : 0u) | code;
}

// ---- prep: norms + fp4 pack (x, -y) + min_dists->out copy ------------------
template<bool PRE>
__global__ void prep_kernel(const float* __restrict__ x, const float* __restrict__ y,
                            float* __restrict__ x2, float* __restrict__ y2,
                            char* __restrict__ xb, char* __restrict__ yb,
                            const float4* __restrict__ mind4, float4* __restrict__ out4,
                            int n4, int B, int M, int nNormBlocks) {
  if ((int)blockIdx.x >= nNormBlocks) {        // tail blocks: full-buffer copy
    int i = ((int)blockIdx.x - nNormBlocks) * 256 + threadIdx.x;
    if (i < n4) out4[i] = mind4[i];
    return;
  }
  int wv = threadIdx.x >> 6;
  int lane = threadIdx.x & 63;
  int row = blockIdx.x * 4 + wv;
  const float* src;
  float* dst;
  char* bdst;
  bool isY;
  if (row < M) {
    isY = true;
    src = y + (size_t)row * DIMS; dst = y2 + row; bdst = yb + (size_t)row * DEXT;
  } else {
    int r = row - M;
    if (r >= B) return;
    isY = false;
    src = x + (size_t)r * DIMS; dst = x2 + r; bdst = xb + (size_t)r * DEXT;
  }
  const float g = isY ? -1.f : 1.f;            // store -y; x(-2) via MX scale
  float s = 0.f;
  #pragma unroll
  for (int h = 0; h < 2; ++h) {
    int c = h * 64 + lane;                     // chunk of 8 k
    const float4* fp = (const float4*)(src + c * 8);
    float4 a0 = fp[0], a1 = fp[1];
    s = fmaf(a0.x, a0.x, s); s = fmaf(a0.y, a0.y, s);
    s = fmaf(a0.z, a0.z, s); s = fmaf(a0.w, a0.w, s);
    s = fmaf(a1.x, a1.x, s); s = fmaf(a1.y, a1.y, s);
    s = fmaf(a1.z, a1.z, s); s = fmaf(a1.w, a1.w, s);
    if (PRE) {
      unsigned w = q4(g * a0.x)        | (q4(g * a0.y) << 4)  |
                   (q4(g * a0.z) << 8) | (q4(g * a0.w) << 12) |
                   (q4(g * a1.x) << 16)| (q4(g * a1.y) << 20) |
                   (q4(g * a1.z) << 24)| (q4(g * a1.w) << 28);
      *(unsigned*)(bdst + c * 4) = w;          // linear k, 4B per 8-elem chunk
    }
  }
  #pragma unroll
  for (int off = 32; off; off >>= 1) s += __shfl_xor(s, off);
  if (lane == 0) *dst = s;
}

// ---------------- phase A: MX-fp4 K=128 MFMA 128x128, dbuf, 4 blocks/CU ----
// r17 structure + T5 setprio around the MFMA cluster + hoisted norm loads.
template<bool PRE>
__global__ __launch_bounds__(256, 4) void knn_mx4(
    const float* __restrict__ xf, const float* __restrict__ yf,
    const char* __restrict__ xb, const char* __restrict__ yb,
    const float* __restrict__ x2, const float* __restrict__ y2,
    float* __restrict__ topk_out,           // [B][128][8] squared dists
    const int* __restrict__ xsp, const int* __restrict__ ysp,
    int B, int M, int nch) {
  __shared__ __align__(16) char smem[32768]; // 2 x (A 8KB + B 8KB)
  const int tid = threadIdx.x;
  const int wv = tid >> 6, l = tid & 63;
  const int wr = wv >> 1, wc = wv & 1;
  const int g4 = l >> 4, l16 = l & 15;
  const int rowblk = blockIdx.x >> 6, colchunk = blockIdx.x & 63;
  const int r0 = rowblk * BM, c0 = colchunk * BN;
  const int xs = *xsp, ys = *ysp;
  const float FINF = __builtin_inff();

  // hoisted epilogue operands: issued before the K-loop, consumed at the end
  const int cb2 = c0 + wc * 64 + g4 * 4;
  float y2v[16];
  #pragma unroll
  for (int ni = 0; ni < 4; ++ni)
    #pragma unroll
    for (int j = 0; j < 4; ++j)
      y2v[ni * 4 + j] = y2[cb2 + ni * 16 + j];
  float x2v[4];
  #pragma unroll
  for (int mi = 0; mi < 4; ++mi)
    x2v[mi] = x2[r0 + wr * 64 + mi * 16 + l16];

  f32x4 acc[4][4];
  #pragma unroll
  for (int mi = 0; mi < 4; ++mi)
    #pragma unroll
    for (int ni = 0; ni < 4; ++ni)
      acc[mi][ni] = (f32x4){0.f, 0.f, 0.f, 0.f};

  // fp4 pair-line LDS layout per tile (8KB = 64 lines x 128B):
  // line = row>>1; slot = ((q ^ (line&3))<<1) | (row&1)  -> 2-way banks (free)
  auto STAGE1 = [&](char* base, int t) {       // one tile pair: 4 gload/thread
    #pragma unroll
    for (int p = 0; p < 2; ++p) {
      int line = p * 32 + (tid >> 3);
      int slot = tid & 7;
      int r = line * 2 + (slot & 1);
      int q = (slot >> 1) ^ (line & 3);        // pre-inverse-swizzled source
      gload_lds16(xb + (size_t)(r0 + r) * DEXT + t * 64 + q * 16,
                  base + p * 4096 + tid * 16);
    }
    #pragma unroll
    for (int p = 0; p < 2; ++p) {
      int line = p * 32 + (tid >> 3);
      int slot = tid & 7;
      int r = line * 2 + (slot & 1);
      int q = (slot >> 1) ^ (line & 3);
      gload_lds16(yb + (size_t)(c0 + r) * DEXT + t * 64 + q * 16,
                  base + 8192 + p * 4096 + tid * 16);
    }
  };

  auto LDFRAG4 = [&](const char* base, int row) -> i32x8 {   // 16B fp4 frag
    int line = row >> 1;
    int slot = ((g4 ^ (line & 3)) << 1) | (row & 1);
    i32x4 v = *(const i32x4*)(base + line * 128 + slot * 16);
    i32x8 r;
    r[0] = v[0]; r[1] = v[1]; r[2] = v[2]; r[3] = v[3];
    r[4] = 0; r[5] = 0; r[6] = 0; r[7] = 0;
    return r;
  };
  auto LDFRAG8 = [&](const char* base, int row) -> i32x8 {   // 32B fp8 frag
    i32x4 lo = *(const i32x4*)(base + row * 128 + (((g4 * 2 + 0) ^ (row & 7)) * 16));
    i32x4 hi = *(const i32x4*)(base + row * 128 + (((g4 * 2 + 1) ^ (row & 7)) * 16));
    i32x8 v;
    v[0] = lo[0]; v[1] = lo[1]; v[2] = lo[2]; v[3] = lo[3];
    v[4] = hi[0]; v[5] = hi[1]; v[6] = hi[2]; v[7] = hi[3];
    return v;
  };

  auto COMPUTE1 = [&](const char* base) {      // one fp4 tile (K=128)
    const char* bb = base + 8192;
    i32x8 bf[4];
    #pragma unroll
    for (int ni = 0; ni < 4; ++ni)
      bf[ni] = LDFRAG4(bb, wc * 64 + ni * 16 + l16);
    #pragma unroll
    for (int mi = 0; mi < 4; ++mi) {
      i32x8 a = LDFRAG4(base, wr * 64 + mi * 16 + l16);
      __builtin_amdgcn_s_setprio(1);           // T5: favor MFMA-issuing wave
      #pragma unroll
      for (int ni = 0; ni < 4; ++ni)           // swapped: C[ycol][xrow]
        acc[mi][ni] = __builtin_amdgcn_mfma_scale_f32_16x16x128_f8f6f4(
            bf[ni], a, acc[mi][ni], 4, 4, 0, SCL2, 0, SCL1);  // fp4; (-y)*2
      __builtin_amdgcn_s_setprio(0);
    }
  };
  auto STAGE_CONV = [&](int t) {               // fallback: f32 -> fp8 in-reg
    #pragma unroll
    for (int p = 0; p < 4; ++p) {
      int row = p * 32 + (tid >> 3);
      int s = (tid & 7) ^ (row & 7);
      {
        const float* g0 = xf + (size_t)(r0 + row) * DIMS + t * 128 + s * 16;
        float4 a0 = *(const float4*)g0, a1 = *(const float4*)(g0 + 4);
        float4 a2 = *(const float4*)(g0 + 8), a3 = *(const float4*)(g0 + 12);
        int w0 = CVT(a0.x, a0.y, 0, 0); w0 = CVT(a0.z, a0.w, w0, 1);
        int w1 = CVT(a1.x, a1.y, 0, 0); w1 = CVT(a1.z, a1.w, w1, 1);
        int w2 = CVT(a2.x, a2.y, 0, 0); w2 = CVT(a2.z, a2.w, w2, 1);
        int w3 = CVT(a3.x, a3.y, 0, 0); w3 = CVT(a3.z, a3.w, w3, 1);
        *(int4*)(smem + p * 4096 + tid * 16) = make_int4(w0, w1, w2, w3);
      }
      {
        const float* g0 = yf + (size_t)(c0 + row) * DIMS + t * 128 + s * 16;
        float4 a0 = *(const float4*)g0, a1 = *(const float4*)(g0 + 4);
        float4 a2 = *(const float4*)(g0 + 8), a3 = *(const float4*)(g0 + 12);
        int w0 = CVT(a0.x, a0.y, 0, 0); w0 = CVT(a0.z, a0.w, w0, 1);
        int w1 = CVT(a1.x, a1.y, 0, 0); w1 = CVT(a1.z, a1.w, w1, 1);
        int w2 = CVT(a2.x, a2.y, 0, 0); w2 = CVT(a2.z, a2.w, w2, 1);
        int w3 = CVT(a3.x, a3.y, 0, 0); w3 = CVT(a3.z, a3.w, w3, 1);
        *(int4*)(smem + 16384 + p * 4096 + tid * 16) = make_int4(w0, w1, w2, w3);
      }
    }
  };

  if (PRE) {
    STAGE1(smem, 0);                           // prologue: tile 0 in flight
    #pragma unroll 1
    for (int t = 0; t < 8; ++t) {
      char* cb = smem + (t & 1) * 16384;
      char* nb = smem + ((t + 1) & 1) * 16384;
      if (t + 1 < 8) {
        STAGE1(nb, t + 1);                     // 4 loads -> other buffer (its
                                               //  readers finished at t-1 bar)
        asm volatile("s_waitcnt vmcnt(4)" ::: "memory");  // tile t landed only
      } else {
        asm volatile("s_waitcnt vmcnt(0)" ::: "memory");
      }
      asm volatile("s_barrier" ::: "memory");  // tile t visible to all waves
      COMPUTE1(cb);
      asm volatile("s_barrier" ::: "memory");  // all waves done reading tile t
    }
  } else {
    #pragma unroll 1
    for (int t = 0; t < DIMS / 128; ++t) {
      __syncthreads();
      STAGE_CONV(t);
      __syncthreads();
      // fp8 tile, unit scales: acc accumulates x.y (note: NOT -2x.y)
      i32x8 bf[4];
      #pragma unroll
      for (int ni = 0; ni < 4; ++ni)
        bf[ni] = LDFRAG8(smem + 16384, wc * 64 + ni * 16 + l16);
      #pragma unroll
      for (int mi = 0; mi < 4; ++mi) {
        i32x8 a = LDFRAG8(smem, wr * 64 + mi * 16 + l16);
        #pragma unroll
        for (int ni = 0; ni < 4; ++ni)
          acc[mi][ni] = __builtin_amdgcn_mfma_scale_f32_16x16x128_f8f6f4(
              bf[ni], a, acc[mi][ni], 0, 0, 0, SCL1, 0, SCL1);
      }
    }
  }

  // ---- epilogue: per-lane top-8 of this wave's 64-col strip; direct store --
  #pragma unroll
  for (int mi = 0; mi < 4; ++mi) {
    const int gr = r0 + wr * 64 + mi * 16 + l16;
    const int dmi = xs + gr - ys - cb2;        // equals ni*16+j iff self-pair
    const float xv = x2v[mi];
    float a[8], b[8];
    #pragma unroll
    for (int ni = 0; ni < 2; ++ni)
      #pragma unroll
      for (int j = 0; j < 4; ++j) {
        float sq = PRE ? fmaxf(xv + y2v[ni * 4 + j] + acc[mi][ni][j], 0.f)
                       : fmaxf(xv + y2v[ni * 4 + j] - 2.f * acc[mi][ni][j], 0.f);
        if (dmi == ni * 16 + j) sq = FINF;
        a[ni * 4 + j] = sq;
      }
    #pragma unroll
    for (int ni = 2; ni < 4; ++ni)
      #pragma unroll
      for (int j = 0; j < 4; ++j) {
        float sq = PRE ? fmaxf(xv + y2v[ni * 4 + j] + acc[mi][ni][j], 0.f)
                       : fmaxf(xv + y2v[ni * 4 + j] - 2.f * acc[mi][ni][j], 0.f);
        if (dmi == ni * 16 + j) sq = FINF;
        b[(ni - 2) * 4 + j] = sq;
      }
    sort8(a); sort8(b); merge8(a, b);          // top8 of lane's 16, ascending
    #pragma unroll
    for (int k = 0; k < 8; ++k) b[k] = __shfl_xor(a[k], 16);
    merge8(a, b);
    #pragma unroll
    for (int k = 0; k < 8; ++k) b[k] = __shfl_xor(a[k], 32);
    merge8(a, b);                              // top8 of the strip's 64 cols
    if (g4 == 0) {                             // one writer per row per strip
      float* o = topk_out + ((size_t)gr * nch + (colchunk * 2 + wc)) * 8;
      *(f32x4*)o       = (f32x4){a[0], a[1], a[2], a[3]};
      *((f32x4*)o + 1) = (f32x4){a[4], a[5], a[6], a[7]};
    }
  }
}

// ---------------- phase B: wave-per-row merge of nch=128 sorted lists ------
__global__ void knn_phaseB(const float* __restrict__ topk,
                           const float* __restrict__ mind_in,
                           float* __restrict__ out,
                           const int* __restrict__ xsp, int B, int nch) {
  int w = threadIdx.x >> 6, lane = threadIdx.x & 63;
  int r = blockIdx.x * 4 + w;
  if (r >= B) return;
  int x_start = *xsp;
  const float* bp = topk + ((size_t)r * nch + lane) * 8;
  const float* bq = topk + ((size_t)r * nch + lane + 64) * 8;
  float t8[8], u8[8];
  f32x4 v0 = *(const f32x4*)bp, v1 = *(const f32x4*)(bp + 4);
  f32x4 w0 = *(const f32x4*)bq, w1 = *(const f32x4*)(bq + 4);
  t8[0]=v0[0]; t8[1]=v0[1]; t8[2]=v0[2]; t8[3]=v0[3];
  t8[4]=v1[0]; t8[5]=v1[1]; t8[6]=v1[2]; t8[7]=v1[3];
  u8[0]=w0[0]; u8[1]=w0[1]; u8[2]=w0[2]; u8[3]=w0[3];
  u8[4]=w1[0]; u8[5]=w1[1]; u8[6]=w1[2]; u8[7]=w1[3];
  merge8(t8, u8);                              // both ascending already
  #pragma unroll
  for (int off = 32; off >= 1; off >>= 1) {    // butterfly merge
    float b[8];
    #pragma unroll
    for (int k = 0; k < 8; ++k) b[k] = __shfl_xor(t8[k], off);
    merge8(t8, b);
  }
  if (lane == 0) {
    float lst[8];
    #pragma unroll
    for (int k = 0; k < 8; ++k) lst[k] = sqrtf(t8[k]);   // squared -> distance
    float cur[8];
    const float* cp = mind_in + (size_t)(x_start + r) * KNN_K;
    #pragma unroll
    for (int k = 0; k < 8; ++k) cur[k] = cp[k];
    sort8(cur);
    merge8(lst, cur);
    #pragma unroll
    for (int k = 0; k < 8; ++k) out[(size_t)(x_start + r) * KNN_K + k] = lst[k];
  }
}

extern "C" void kernel_launch(void* const* d_in, const int* in_sizes, int n_in,
                              void* d_out, int out_size, void* d_ws, size_t ws_size,
                              hipStream_t stream) {
  const float* x = (const float*)d_in[0];
  const float* y = (const float*)d_in[1];
  const float* mind = (const float*)d_in[2];
  const int* xsp = (const int*)d_in[3];
  const int* ysp = (const int*)d_in[4];
  float* out = (float*)d_out;

  const int B = in_sizes[0] / DIMS;       // 2048
  const int M = in_sizes[1] / DIMS;       // 8192
  const int nch = M / 64;                 // 128 strips of 64 cols

  float* y2 = (float*)d_ws;               // [M]
  float* x2 = y2 + M;                     // [B]
  float* topk = x2 + B;                   // [B][nch][8]
  size_t base = ((size_t)(M + B) + (size_t)B * nch * 8) * 4;
  base = (base + 255) & ~(size_t)255;
  char* xbw = (char*)d_ws + base;
  char* ybw = xbw + (size_t)B * DEXT;
  size_t need = base + ((size_t)B + (size_t)M) * DEXT;
  bool pre = ws_size >= need;

  int nNorm = (B + M + 3) / 4;
  int n4 = out_size / 4;
  int nCopy = (n4 + 255) / 256;
  if (pre)
    prep_kernel<true><<<nNorm + nCopy, 256, 0, stream>>>(
        x, y, x2, y2, xbw, ybw, (const float4*)mind, (float4*)out, n4, B, M, nNorm);
  else
    prep_kernel<false><<<nNorm + nCopy, 256, 0, stream>>>(
        x, y, x2, y2, xbw, ybw, (const float4*)mind, (float4*)out, n4, B, M, nNorm);

  int nBlocks = (B / BM) * (M / BN);      // 16 x 64 = 1024 (4 blocks/CU)
  if (pre)
    knn_mx4<true><<<nBlocks, 256, 0, stream>>>(x, y, xbw, ybw, x2, y2, topk, xsp, ysp, B, M, nch);
  else
    knn_mx4<false><<<nBlocks, 256, 0, stream>>>(x, y, xbw, ybw, x2, y2, topk, xsp, ysp, B, M, nch);

  knn_phaseB<<<(B + 3) / 4, 256, 0, stream>>>(topk, mind, out, xsp, B, nch);
}